// Round 8
// baseline (382.487 us; speedup 1.0000x reference)
//
#include <hip/hip_runtime.h>
#include <hip/hip_cooperative_groups.h>

namespace cg = cooperative_groups;

#define BATCH 128
#define NBOX 8732
#define NC 21
#define M (BATCH * NBOX)            // 1,117,696 = 4366 * 256
#define NBLK (M / 256)              // 4366
#define NREP1 32                    // L1 replicas
#define NREP2 8                     // L2/L3 replicas
#define NB1 1024                    // L1 bins (10 bits)
#define NB23 2048                   // L2/L3 bins (11 bits)
#define PGRID 256                   // cooperative grid: 1 block/CU
#define CLIP_MAX 16.118095651f      // -log(1e-7)

struct Ctl {
  float num_pos[BATCH];
  float pos_conf_sum, pos_loc_sum, s_gt, denom;
  unsigned int k_rem, d1, d2, pad;
};

// ws layout: [ctl][rep1 c/s][rep2 c/s][rep3 c/s][pc_part][pl_part][MC][CL]
#define OFF_R1C 1024
#define R1SZ    (NREP1 * NB1 * 4)        // 131072
#define R23SZ   (NREP2 * NB23 * 4)       // 65536
#define OFF_R1S (OFF_R1C + R1SZ)
#define OFF_R2C (OFF_R1S + R1SZ)
#define OFF_R2S (OFF_R2C + R23SZ)
#define OFF_R3C (OFF_R2S + R23SZ)
#define OFF_R3S (OFF_R3C + R23SZ)
#define OFF_PCP (OFF_R3S + R23SZ)
#define ZERO_BYTES OFF_PCP               // 525,312 B (ctl + all replicas)
#define OFF_PLP (OFF_PCP + 17472)
#define OFF_MC  (OFF_PLP + 17472)
#define OFF_CL  (OFF_MC + M * 4)         // total ~9.1 MB

// 32-bit linear fixed-point key over [0,1]: monotone in mc; injective for
// mc > 2^-8 (float spacing > 2^-32 grid there). Threshold lives at mc~0.5-1.
// Digits: 10 | 11 | 11.
__device__ __forceinline__ unsigned int mckey(float mc) {
  unsigned long long K = (unsigned long long)((double)mc * 4294967296.0);
  return (K > 0xFFFFFFFFull) ? 0xFFFFFFFFu : (unsigned int)K;
}

// ---------------------------------------------------------------------------
// Fused elementwise + L1 histogram. One row per thread, straight-line: all 35
// loads (21 conf + 13 y_true float2 + 1 loc float4) independent -> deep MLP.
// Latency-bound regime: throughput ~ waves x outstanding loads.
// ---------------------------------------------------------------------------
__global__ __launch_bounds__(256, 4) void k_elem(
    const float* __restrict__ yt, const float* __restrict__ lp,
    const float* __restrict__ cp, float* __restrict__ MC,
    float* __restrict__ CL, float* __restrict__ pc_part,
    float* __restrict__ pl_part, unsigned int* __restrict__ rep1c,
    float* __restrict__ rep1s, Ctl* __restrict__ ctl) {
  __shared__ unsigned int hc[NB1];     // 4 KB
  __shared__ float hs[NB1];            // 4 KB
  __shared__ float sred[16];

  const int tid = threadIdx.x;
  const int bid = blockIdx.x;
  const int e = bid * 256 + tid;

  for (int i = tid; i < NB1; i += 256) { hc[i] = 0u; hs[i] = 0.f; }

  // ---- issue all row loads up front (independent)
  const float4 lv = ((const float4*)lp)[e];            // 16B aligned
  float2 yw[13];                                       // rows 104B -> 8B aligned
  {
    const float2* y2 = (const float2*)(yt + (size_t)e * 26);
#pragma unroll
    for (int j = 0; j < 13; ++j) yw[j] = y2[j];
  }
  float cv[NC];                                        // rows 84B -> scalar dwords
  {
    const float* crow = cp + (size_t)e * NC;
#pragma unroll
    for (int j = 0; j < NC; ++j) cv[j] = crow[j];
  }
  __syncthreads();   // hist zero visible before any atomics below

  const float pos = yw[12].y;

  // smooth-L1 loc loss
  const float d0 = yw[0].x - lv.x, d1 = yw[0].y - lv.y;
  const float d2 = yw[1].x - lv.z, d3 = yw[1].y - lv.w;
  const float a0 = fabsf(d0), a1 = fabsf(d1), a2 = fabsf(d2), a3 = fabsf(d3);
  const float ll = ((a0 < 1.f) ? 0.5f * d0 * d0 : a0 - 0.5f)
                 + ((a1 < 1.f) ? 0.5f * d1 * d1 : a1 - 0.5f)
                 + ((a2 < 1.f) ? 0.5f * d2 * d2 : a2 - 0.5f)
                 + ((a3 < 1.f) ? 0.5f * d3 * d3 : a3 - 0.5f);

  // softmax stats (all static indexing)
  float mx = cv[0];
#pragma unroll
  for (int j = 1; j < NC; ++j) mx = fmaxf(mx, cv[j]);
  float plogit = 0.f;             // onehot dot logits: exact label-logit select
#pragma unroll
  for (int j = 0; j < NC; ++j) {
    const int w = 4 + j;
    const float oh = (w & 1) ? yw[w >> 1].y : yw[w >> 1].x;
    plogit = fmaf(oh, cv[j], plogit);
  }
  float ssum = 0.f, e0 = 0.f;
#pragma unroll
  for (int j = 0; j < NC; ++j) {
    const float ee = __expf(cv[j] - mx);
    ssum += ee;
    if (j == 0) e0 = ee;
  }
  const float cl = fminf(mx + __logf(ssum) - plogit, CLIP_MAX);
  const float mc = (1.f - pos) * ((ssum - e0) / ssum);

  MC[e] = mc;
  CL[e] = cl;
  const unsigned int b1 = mckey(mc) >> 22;   // top 10 bits
  atomicAdd(&hc[b1], 1u);
  atomicAdd(&hs[b1], cl);

  // block reductions; a block spans at most 2 batches
  const int b0 = (bid << 8) / NBOX;
  float np0 = (e < (b0 + 1) * NBOX) ? pos : 0.f;
  float np1 = pos - np0;
  float tpc = pos * cl, tpl = pos * ll;
#pragma unroll
  for (int off = 32; off > 0; off >>= 1) {
    tpc += __shfl_down(tpc, off);
    tpl += __shfl_down(tpl, off);
    np0 += __shfl_down(np0, off);
    np1 += __shfl_down(np1, off);
  }
  if ((tid & 63) == 0) {
    const int w = tid >> 6;
    sred[w] = tpc; sred[4 + w] = tpl; sred[8 + w] = np0; sred[12 + w] = np1;
  }
  __syncthreads();   // sred ready; also orders LDS hist atomics before flush
  if (tid == 0) {
    pc_part[bid] = sred[0] + sred[1] + sred[2] + sred[3];
    pl_part[bid] = sred[4] + sred[5] + sred[6] + sred[7];
    const float n0 = sred[8] + sred[9] + sred[10] + sred[11];
    const float n1 = sred[12] + sred[13] + sred[14] + sred[15];
    if (n0 != 0.f) atomicAdd(&ctl->num_pos[b0], n0);
    if (n1 != 0.f && b0 + 1 < BATCH) atomicAdd(&ctl->num_pos[b0 + 1], n1);
  }
  unsigned int* rc = rep1c + (bid & (NREP1 - 1)) * NB1;
  float* rs = rep1s + (bid & (NREP1 - 1)) * NB1;
  for (int i = tid; i < NB1; i += 256)
    if (hc[i]) { atomicAdd(&rc[i], hc[i]); atomicAdd(&rs[i], hs[i]); }
}

// ---------------------------------------------------------------------------
// Cooperative post-processing: scan1 | hist2 | scan2 | hist3 | scan3 as five
// phases in ONE dispatch (kills ~5 x per-dispatch overhead).
// ---------------------------------------------------------------------------
template <int LEVEL>
__device__ void hist_phase(const float* MC, const float* CL,
                           unsigned int* repc, float* reps,
                           unsigned int* hc, float* hs,
                           unsigned int d1v, unsigned int d2v) {
  const int tid = threadIdx.x;
  for (int i = tid; i < NB23; i += 1024) { hc[i] = 0u; hs[i] = 0.f; }
  __syncthreads();
  const unsigned int dd = (LEVEL == 2) ? d1v : ((d1v << 11) | d2v);
  const float4* M4 = (const float4*)MC;
  const int n4 = M / 4;
  const int stride = PGRID * 1024;
  for (int i = blockIdx.x * 1024 + tid; i < n4; i += stride) {
    const float4 m = M4[i];
    const float mv[4] = {m.x, m.y, m.z, m.w};
#pragma unroll
    for (int q = 0; q < 4; ++q) {
      const unsigned int K = mckey(mv[q]);
      bool match; unsigned int bin;
      if (LEVEL == 2) { match = (K >> 22) == dd; bin = (K >> 11) & 2047u; }
      else            { match = (K >> 11) == dd; bin = K & 2047u; }
      if (match) { atomicAdd(&hc[bin], 1u); atomicAdd(&hs[bin], CL[4 * i + q]); }
    }
  }
  __syncthreads();
  unsigned int* rc = repc + (blockIdx.x & (NREP2 - 1)) * NB23;
  float* rs = reps + (blockIdx.x & (NREP2 - 1)) * NB23;
  for (int i = tid; i < NB23; i += 1024)
    if (hc[i]) { atomicAdd(&rc[i], hc[i]); atomicAdd(&rs[i], hs[i]); }
}

// rbuf layout: [0:16) red | [16:32) rn | [32:48) rh | [48:64) rc | [64:80) ra | [80:96) rb
template <int LEVEL, int NREP, int NBINS>
__device__ void scan_phase(unsigned int* s, float* sf, float* rbuf,
                           unsigned int* kkp, int* winp,
                           const unsigned int* repc, const float* reps,
                           const float* pc_part, const float* pl_part,
                           Ctl* ctl, float* out) {
  const int tid = threadIdx.x;
  unsigned int c0 = 0, c1 = 0;
  float f0 = 0.f, f1 = 0.f;
  for (int r = 0; r < NREP; ++r) {
    c0 += repc[r * NBINS + tid];
    f0 += reps[r * NBINS + tid];
    if (NBINS > 1024) {
      c1 += repc[r * NBINS + tid + 1024];
      f1 += reps[r * NBINS + tid + 1024];
    }
  }
  s[tid] = c0; s[tid + 1024] = c1;
  sf[tid] = f0; sf[tid + 1024] = f1;

  if (LEVEL == 1) {
    const float np = (tid < BATCH) ? ctl->num_pos[tid] : 0.f;
    float nn  = fminf(3.0f * np, (float)NBOX - np);
    float hp  = (np > 0.f) ? 1.f : 0.f;
    float npc = (tid < BATCH) ? ((np != 0.f) ? np : 1.f) : 0.f;
    float a = 0.f, b = 0.f;
    for (int i = tid; i < NBLK; i += 1024) { a += pc_part[i]; b += pl_part[i]; }
#pragma unroll
    for (int off = 32; off > 0; off >>= 1) {
      nn += __shfl_down(nn, off);   hp += __shfl_down(hp, off);
      npc += __shfl_down(npc, off); a += __shfl_down(a, off);
      b += __shfl_down(b, off);
    }
    const int w = tid >> 6;
    if ((tid & 63) == 0) {
      rbuf[16 + w] = nn; rbuf[32 + w] = hp; rbuf[48 + w] = npc;
      rbuf[64 + w] = a;  rbuf[80 + w] = b;
    }
    __syncthreads();
    if (tid == 0) {
      float tn = 0.f, th = 0.f, tc = 0.f, ta = 0.f, tb = 0.f;
      for (int i = 0; i < 16; ++i) {
        tn += rbuf[16 + i]; th += rbuf[32 + i]; tc += rbuf[48 + i];
        ta += rbuf[64 + i]; tb += rbuf[80 + i];
      }
      ctl->denom = tc;
      ctl->pos_conf_sum = ta;
      ctl->pos_loc_sum = tb;
      *kkp = (unsigned int)floorf((th > 0.f) ? tn : 100.0f);   // NEG_FOR_HARD
    }
  } else {
    if (tid == 0) *kkp = *(volatile unsigned int*)&ctl->k_rem;
  }
  if (tid == 0) *winp = -1;
  __syncthreads();

  const unsigned int krem = *kkp;   // uniform
  if (krem != 0) {
    for (int off = 1; off < 2048; off <<= 1) {   // inclusive suffix scan
      const unsigned int v0 = (tid + off < 2048) ? s[tid + off] : 0u;
      const unsigned int v1 = (tid + 1024 + off < 2048) ? s[tid + 1024 + off] : 0u;
      __syncthreads();
      s[tid] += v0;
      s[tid + 1024] += v1;
      __syncthreads();
    }
#pragma unroll
    for (int t = 0; t < 2; ++t) {   // unique b*: suffix[b*] >= k > suffix[b*+1]
      const int i = tid + t * 1024;
      const unsigned int si = s[i];
      const unsigned int sn = (i < 2047) ? s[i + 1] : 0u;
      if (si >= krem && sn < krem) *winp = i;
    }
    __syncthreads();
    const int b = *winp;   // uniform
    float acc = 0.f;       // CL of fully-selected bins (strictly above b*)
    if (b >= 0) {
      if (tid > b) acc += sf[tid];
      if (tid + 1024 > b) acc += sf[tid + 1024];
    }
#pragma unroll
    for (int off = 32; off > 0; off >>= 1) acc += __shfl_down(acc, off);
    if ((tid & 63) == 0) rbuf[tid >> 6] = acc;
    __syncthreads();
    if (tid == 0 && b >= 0) {
      float tot = 0.f;
      for (int i = 0; i < 16; ++i) tot += rbuf[i];
      const unsigned int above = (b < 2047) ? s[b + 1] : 0u;
      const unsigned int krem2 = krem - above;
      if (LEVEL < 3) {
        ctl->s_gt += tot;
        ctl->k_rem = krem2;
        if (LEVEL == 1) ctl->d1 = (unsigned int)b;
        else            ctl->d2 = (unsigned int)b;
      } else {
        const unsigned int neq = s[b] - above;   // ties: bit-identical keys
        const float tie = (neq > 0) ? sf[b] * ((float)krem2 / (float)neq) : 0.f;
        const float neg = ctl->s_gt + tot + tie;
        out[0] = (ctl->pos_conf_sum + neg + ctl->pos_loc_sum) / ctl->denom;
      }
    }
  } else if (LEVEL == 3 && tid == 0) {   // defensive: cannot occur
    out[0] = (ctl->pos_conf_sum + ctl->s_gt + ctl->pos_loc_sum) / ctl->denom;
  }
  __syncthreads();
}

__global__ __launch_bounds__(1024) void k_post(
    const float* MC, const float* CL,
    const unsigned int* rep1c, const float* rep1s,
    unsigned int* rep2c, float* rep2s,
    unsigned int* rep3c, float* rep3s,
    const float* pc_part, const float* pl_part,
    Ctl* ctl, float* out) {
  __shared__ unsigned int s[2048];
  __shared__ float sf[2048];
  __shared__ float rbuf[96];
  __shared__ unsigned int kk;
  __shared__ int win;
  cg::grid_group grid = cg::this_grid();

  if (blockIdx.x == 0)
    scan_phase<1, NREP1, NB1>(s, sf, rbuf, &kk, &win, rep1c, rep1s,
                              pc_part, pl_part, ctl, out);
  grid.sync();
  {
    const unsigned int d1v = *(volatile unsigned int*)&ctl->d1;
    hist_phase<2>(MC, CL, rep2c, rep2s, s, sf, d1v, 0u);
  }
  grid.sync();
  if (blockIdx.x == 0)
    scan_phase<2, NREP2, NB23>(s, sf, rbuf, &kk, &win, rep2c, rep2s,
                               pc_part, pl_part, ctl, out);
  grid.sync();
  {
    const unsigned int d1v = *(volatile unsigned int*)&ctl->d1;
    const unsigned int d2v = *(volatile unsigned int*)&ctl->d2;
    hist_phase<3>(MC, CL, rep3c, rep3s, s, sf, d1v, d2v);
  }
  grid.sync();
  if (blockIdx.x == 0)
    scan_phase<3, NREP2, NB23>(s, sf, rbuf, &kk, &win, rep3c, rep3s,
                               pc_part, pl_part, ctl, out);
}

// ---------------------------------------------------------------------------
extern "C" void kernel_launch(void* const* d_in, const int* in_sizes, int n_in,
                              void* d_out, int out_size, void* d_ws, size_t ws_size,
                              hipStream_t stream) {
  const float* yt = (const float*)d_in[0];   // y_true    (B,N,26)
  const float* lp = (const float*)d_in[1];   // loc_pred  (B,N,4)
  const float* cp = (const float*)d_in[2];   // conf_pred (B,N,21)
  float* out = (float*)d_out;

  char* ws = (char*)d_ws;
  Ctl* ctl = (Ctl*)ws;
  unsigned int* rep1c = (unsigned int*)(ws + OFF_R1C);
  float*        rep1s = (float*)(ws + OFF_R1S);
  unsigned int* rep2c = (unsigned int*)(ws + OFF_R2C);
  float*        rep2s = (float*)(ws + OFF_R2S);
  unsigned int* rep3c = (unsigned int*)(ws + OFF_R3C);
  float*        rep3s = (float*)(ws + OFF_R3S);
  float* pc_part = (float*)(ws + OFF_PCP);
  float* pl_part = (float*)(ws + OFF_PLP);
  float* MC = (float*)(ws + OFF_MC);
  float* CL = (float*)(ws + OFF_CL);

  hipMemsetAsync(ws, 0, ZERO_BYTES, stream);   // ctl + all replicas (0.5 MB)
  k_elem<<<NBLK, 256, 0, stream>>>(yt, lp, cp, MC, CL, pc_part, pl_part,
                                   rep1c, rep1s, ctl);
  void* args[] = {&MC, &CL, &rep1c, &rep1s, &rep2c, &rep2s, &rep3c, &rep3s,
                  &pc_part, &pl_part, &ctl, &out};
  hipLaunchCooperativeKernel((void*)k_post, dim3(PGRID), dim3(1024), args, 0,
                             stream);
}